// Round 1
// baseline (893.785 us; speedup 1.0000x reference)
//
#include <hip/hip_runtime.h>

typedef unsigned short us;
typedef us us4 __attribute__((ext_vector_type(4)));
typedef us us8 __attribute__((ext_vector_type(8)));
typedef short bf16x8 __attribute__((ext_vector_type(8)));
typedef float f32x4 __attribute__((ext_vector_type(4)));

#define DEVI static __device__ __forceinline__

// constants for this problem instance
#define BB 16
#define NN 4096
#define PP 256
#define CC 8
#define MM (BB * NN)   // 65536

DEVI float bf2f(us u) { unsigned x = ((unsigned)u) << 16; return __builtin_bit_cast(float, x); }
DEVI us f2bf(float f) {
  unsigned x = __builtin_bit_cast(unsigned, f);
  x += 0x7fffu + ((x >> 16) & 1u);   // round to nearest even
  return (us)(x >> 16);
}

DEVI void gload_lds16(const void* g, void* l) {
  __builtin_amdgcn_global_load_lds(
      (const __attribute__((address_space(1))) void*)g,
      (__attribute__((address_space(3))) void*)l, 16, 0, 0);
}

// ---------------- weight prep: fp32 -> bf16, concatenated / gate-interleaved ----
__global__ void k_prep(const float* __restrict__ Wres,
                       const float* __restrict__ Wpar, const float* __restrict__ bpar,
                       const float* __restrict__ Wnbr, const float* __restrict__ bnbr,
                       const float* __restrict__ Wih, const float* __restrict__ Whh,
                       const float* __restrict__ bih, const float* __restrict__ bhh,
                       us* __restrict__ Wr, us* __restrict__ Wcat, float* __restrict__ bcat,
                       us* __restrict__ Wg, float* __restrict__ bg) {
  int tid = blockIdx.x * blockDim.x + threadIdx.x;
  int nth = gridDim.x * blockDim.x;
  for (int i = tid; i < 256 * 256; i += nth) Wr[i] = f2bf(Wres[i]);
  for (int i = tid; i < 256 * 512; i += nth) {
    int o = i >> 9, k = i & 511;
    float v = (k < 256) ? Wpar[o * 256 + k] : Wnbr[o * 256 + (k - 256)];
    Wcat[i] = f2bf(v);
  }
  for (int i = tid; i < 256; i += nth) bcat[i] = bpar[i] + bnbr[i];
  // Wg row 4j+t over K=512 ([h | s]):
  // t=0: [W_ih_r | W_hh_r], t=1: [W_ih_z | W_hh_z], t=2: [W_ih_n | 0], t=3: [0 | W_hh_n]
  for (int i = tid; i < 1024 * 512; i += nth) {
    int R = i >> 9, k = i & 511;
    int j = R >> 2, t = R & 3;
    float v = 0.f;
    if (t == 0)      v = (k < 256) ? Wih[j * 256 + k]         : Whh[j * 256 + (k - 256)];
    else if (t == 1) v = (k < 256) ? Wih[(256 + j) * 256 + k] : Whh[(256 + j) * 256 + (k - 256)];
    else if (t == 2) v = (k < 256) ? Wih[(512 + j) * 256 + k] : 0.f;
    else             v = (k < 256) ? 0.f                      : Whh[(512 + j) * 256 + (k - 256)];
    Wg[i] = f2bf(v);
  }
  for (int i = tid; i < 1024; i += nth) {
    int j = i >> 2, t = i & 3;
    float v;
    if (t == 0)      v = bih[j] + bhh[j];
    else if (t == 1) v = bih[256 + j] + bhh[256 + j];
    else if (t == 2) v = bih[512 + j];
    else             v = bhh[512 + j];
    bg[i] = v;
  }
}

// ---------------- x fp32 -> bf16 (vectorized) ----------------
__global__ __launch_bounds__(256) void k_f2bf(const float* __restrict__ x,
                                              us* __restrict__ o, int n8) {
  int i = blockIdx.x * blockDim.x + threadIdx.x;
  if (i >= n8) return;
  const float4* p = (const float4*)x + (size_t)i * 2;
  float4 a = p[0], b = p[1];
  us8 r;
  r[0] = f2bf(a.x); r[1] = f2bf(a.y); r[2] = f2bf(a.z); r[3] = f2bf(a.w);
  r[4] = f2bf(b.x); r[5] = f2bf(b.y); r[6] = f2bf(b.z); r[7] = f2bf(b.w);
  *(us8*)(o + (size_t)i * 8) = r;
}

// ---------------- gather: A_cat = [h[parent] | avg children h] (bf16) ----------
__global__ __launch_bounds__(256)
void k_gather(const us* __restrict__ h, const int* __restrict__ par,
              const int* __restrict__ chd, const int* __restrict__ cnt,
              us* __restrict__ Acat) {
  int wid = (blockIdx.x * blockDim.x + threadIdx.x) >> 6;  // one wave per node
  int l = threadIdx.x & 63;
  int m = wid;                       // 0..MM-1
  int b = m >> 12;                   // N = 4096
  int rowP = (b << 12) + par[m];
  us4 pv = *((const us4*)(h + ((size_t)rowP << 8)) + l);
  *((us4*)(Acat + ((size_t)m << 9)) + l) = pv;
  int c = cnt[m];
  float inv = 1.f / (float)c;
  float a0 = 0.f, a1 = 0.f, a2 = 0.f, a3 = 0.f;
  const int* ch = chd + (size_t)m * CC;
  for (int i = 0; i < c; ++i) {
    int rowC = (b << 12) + ch[i];
    us4 cv = *((const us4*)(h + ((size_t)rowC << 8)) + l);
    a0 += bf2f(cv[0]); a1 += bf2f(cv[1]); a2 += bf2f(cv[2]); a3 += bf2f(cv[3]);
  }
  us4 nb;
  nb[0] = f2bf(a0 * inv); nb[1] = f2bf(a1 * inv);
  nb[2] = f2bf(a2 * inv); nb[3] = f2bf(a3 * inv);
  *((us4*)(Acat + ((size_t)m << 9) + 256) + l) = nb;
}

// ---------------- GEMM: C = A @ Bw^T (+bias), m97-style 128x128 tile ----------
// A virtual-concat along K: k < kSplit -> A0, else A1 (both stride strideA).
// EPI 0: write bf16.  EPI 1: write bf16 + f32.  EPI 2: fused GRU epilogue.
template <int EPI>
__global__ __launch_bounds__(256, 2)
void k_gemm(const us* __restrict__ A0, const us* __restrict__ A1,
            int kSplit, int strideA,
            const us* __restrict__ Bw, int kTot,
            const float* __restrict__ bias,
            us* __restrict__ outBf, float* __restrict__ outF,
            const float* __restrict__ sF, int writeF32) {
  __shared__ __align__(16) us As[128 * 64];
  __shared__ __align__(16) us Bs[128 * 64];
  int tid = threadIdx.x;
  int w = tid >> 6, l = tid & 63;
  int wr = w >> 1, wc = w & 1;
  int mBase = blockIdx.x * 128, nBase = blockIdx.y * 128;
  f32x4 acc[4][4] = {};

  for (int kt = 0; kt < kTot; kt += 64) {
    const us* aSrc; int kOff;
    if (kt < kSplit) { aSrc = A0; kOff = kt; }
    else             { aSrc = A1; kOff = kt - kSplit; }
#pragma unroll
    for (int c = 0; c < 4; ++c) {
      int row = c * 32 + w * 8 + (l >> 3);
      int kb = ((l & 7) * 16) ^ ((row & 7) << 4);   // pre-swizzled global source
      const char* ga = (const char*)(aSrc + (size_t)(mBase + row) * strideA + kOff) + kb;
      gload_lds16(ga, (char*)As + row * 128 + (l & 7) * 16);
      const char* gb = (const char*)(Bw + (size_t)(nBase + row) * kTot + kt) + kb;
      gload_lds16(gb, (char*)Bs + row * 128 + (l & 7) * 16);
    }
    asm volatile("s_waitcnt vmcnt(0)" ::: "memory");
    __syncthreads();
#pragma unroll
    for (int ks = 0; ks < 2; ++ks) {
      bf16x8 af[4], bfr[4];
#pragma unroll
      for (int i = 0; i < 4; ++i) {
        int row = wr * 64 + i * 16 + (l & 15);
        int kb = ((ks * 32 + (l >> 4) * 8) * 2) ^ ((row & 7) << 4);  // swizzled read
        af[i] = *(const bf16x8*)((const char*)As + row * 128 + kb);
      }
#pragma unroll
      for (int j = 0; j < 4; ++j) {
        int row = wc * 64 + j * 16 + (l & 15);
        int kb = ((ks * 32 + (l >> 4) * 8) * 2) ^ ((row & 7) << 4);
        bfr[j] = *(const bf16x8*)((const char*)Bs + row * 128 + kb);
      }
#pragma unroll
      for (int i = 0; i < 4; ++i)
#pragma unroll
        for (int j = 0; j < 4; ++j)
          acc[i][j] = __builtin_amdgcn_mfma_f32_16x16x32_bf16(af[i], bfr[j], acc[i][j], 0, 0, 0);
    }
    __syncthreads();
  }

  int rBase0 = mBase + wr * 64;
  int cBase0 = nBase + wc * 64;
  if (EPI == 0 || EPI == 1) {
#pragma unroll
    for (int i = 0; i < 4; ++i)
#pragma unroll
      for (int j = 0; j < 4; ++j) {
        int col = cBase0 + j * 16 + (l & 15);
        int row0 = rBase0 + i * 16 + ((l >> 4) << 2);
        float bb = bias[col];
#pragma unroll
        for (int e = 0; e < 4; ++e) {
          float v = acc[i][j][e] + bb;
          size_t off = (size_t)(row0 + e) * 256 + col;
          outBf[off] = f2bf(v);
          if (EPI == 1) outF[off] = v;
        }
      }
  } else {
    // EPI 2: cols are gate-interleaved (4j+t, t = r,z,xn,hn). Quad butterfly
    // then GRU math; lane t writes row rBase+t's output (reg e == t).
    int t = l & 3;
#pragma unroll
    for (int i = 0; i < 4; ++i)
#pragma unroll
      for (int j = 0; j < 4; ++j) {
        int col = cBase0 + j * 16 + (l & 15);
        int row0 = rBase0 + i * 16 + ((l >> 4) << 2);
        int J = col >> 2;
        float bb = bias[col];
#pragma unroll
        for (int e = 0; e < 4; ++e) {
          float v = acc[i][j][e] + bb;       // gate t of row row0+e
          float x1 = __shfl_xor(v, 1);       // gate t^1
          float x2 = __shfl_xor(v, 2);       // gate t^2
          float x3 = __shfl_xor(x1, 2);      // gate t^3
          float g0 = v, g1 = x1, g2 = x2, g3 = x3;  // positions [t, t^1, t^2, t^3]
          if (t & 1) { float tm = g0; g0 = g1; g1 = tm; tm = g2; g2 = g3; g3 = tm; }
          if (t & 2) { float tm = g0; g0 = g2; g2 = tm; tm = g1; g1 = g3; g3 = tm; }
          // g0=r_pre, g1=z_pre, g2=xn, g3=hn  (all lanes of quad identical now)
          if (t == e) {
            float r = 1.f / (1.f + __expf(-g0));
            float z = 1.f / (1.f + __expf(-g1));
            float n = tanhf(g2 + r * g3);
            size_t off = (size_t)(row0 + e) * 256 + J;
            float sv = sF[off];
            float o = (1.f - z) * n + z * sv;
            if (writeF32) outF[off] = o;
            else          outBf[off] = f2bf(o);
          }
        }
      }
  }
}

extern "C" void kernel_launch(void* const* d_in, const int* in_sizes, int n_in,
                              void* d_out, int out_size, void* d_ws, size_t ws_size,
                              hipStream_t stream) {
  const float* x    = (const float*)d_in[0];
  const int*   par  = (const int*)d_in[1];
  const int*   chd  = (const int*)d_in[2];
  const int*   cnt  = (const int*)d_in[3];
  const float* Wres = (const float*)d_in[4];
  const float* bres = (const float*)d_in[5];
  const float* Wpar = (const float*)d_in[6];
  const float* bpar = (const float*)d_in[7];
  const float* Wnbr = (const float*)d_in[8];
  const float* bnbr = (const float*)d_in[9];
  const float* Wih  = (const float*)d_in[10];
  const float* Whh  = (const float*)d_in[11];
  const float* bih  = (const float*)d_in[12];
  const float* bhh  = (const float*)d_in[13];

  char* ws = (char*)d_ws;
  size_t off = 0;
  auto alloc = [&](size_t sz) { char* p = ws + off; off += (sz + 255) & ~(size_t)255; return p; };
  us*    Wg   = (us*)alloc((size_t)1024 * 512 * 2);
  us*    Wcat = (us*)alloc((size_t)256 * 512 * 2);
  us*    Wr   = (us*)alloc((size_t)256 * 256 * 2);
  float* bcat = (float*)alloc(256 * 4);
  float* bg   = (float*)alloc(1024 * 4);
  us*    xbf  = (us*)alloc((size_t)MM * 256 * 2);  // reused as s_bf after resize
  us*    h0   = (us*)alloc((size_t)MM * 256 * 2);
  us*    h1   = (us*)alloc((size_t)MM * 256 * 2);
  us*    Acat = (us*)alloc((size_t)MM * 512 * 2);
  us*    sbf  = xbf;
  float* sF   = (float*)d_out;  // s_f32 scratch lives in d_out (overwritten at end)

  k_prep<<<256, 256, 0, stream>>>(Wres, Wpar, bpar, Wnbr, bnbr, Wih, Whh, bih, bhh,
                                  Wr, Wcat, bcat, Wg, bg);
  k_f2bf<<<(MM * 256 / 8) / 256, 256, 0, stream>>>(x, xbf, MM * 256 / 8);

  // h0 = x @ W_resize^T + b_resize
  k_gemm<0><<<dim3(MM / 128, 2), 256, 0, stream>>>(
      xbf, xbf, 256, 256, Wr, 256, bres, h0, nullptr, nullptr, 0);

  us* hc = h0;
  for (int it = 0; it < 3; ++it) {
    us* hn = (hc == h0) ? h1 : h0;
    k_gather<<<MM / 4, 256, 0, stream>>>(hc, par, chd, cnt, Acat);
    // s = [p|m] @ Wcat^T + bcat  -> s_bf + s_f32(in d_out)
    k_gemm<1><<<dim3(MM / 128, 2), 256, 0, stream>>>(
        Acat, Acat, 512, 512, Wcat, 512, bcat, sbf, sF, nullptr, 0);
    // fused GRU: [h|s] @ Wg^T, gate epilogue -> h_next (bf16) or d_out (f32, last)
    k_gemm<2><<<dim3(MM / 128, 8), 256, 0, stream>>>(
        hc, sbf, 256, 256, Wg, 512, bg, hn, (float*)d_out, sF, (it == 2) ? 1 : 0);
    hc = hn;
  }
}